// Round 8
// baseline (724.789 us; speedup 1.0000x reference)
//
#include <hip/hip_runtime.h>
#include <hip/hip_bf16.h>

// ---------------------------------------------------------------------------
// GCN 2-layer forward on MI355X (gfx950).
// R6 lesson: agg gather rate (2.7 TB/s) is the random-256B-granule DRAM floor
// (4-deep and 8-deep identical; FETCH = 8 XCD x 25.6 MB compulsory minimum).
// This round deletes the layer-2 GEMM via distributivity:
//   sum_s dinv_s*(a1_s @ W2) = (sum_s dinv_s*a1_s) @ W2
// so agg2 gathers a1 directly (same bytes) and applies W2 in a per-wave GEMV
// epilogue (after shfl_xor(32), ALL 64 lanes hold the full 128-dim y; 32
// broadcast shfls + 256 fma; W2 stays f32, L2-hot). Removes: gemm2 dispatch,
// its 51MB g2 round-trip, the Wt2 cvt, and one bf16 rounding.
// R7 fix: __builtin_nontemporal_store rejects HIP float2 (class type) ->
// use ext_vector_type f32x2 (same as uint2e/f32x4 pattern).
// Pipeline (5 launches):
//   K0 cvt_zero : W1 f32->bf16 transpose (128 blocks) + zero bcnt
//   K1 fused1   : blocks [0,NBB) bucket-bin edges; blocks [NBB,..) gemm1
//   K2 scatter2 : inline 196-scan of bcnt; deg->dinv; rowptr; einfo
//                 (bucket windows keep einfo writes CU-local; R5: global
//                 atomic scatter = 16x write-amp, 133us)
//   K3 agg1     : gather+fma(dinv[s]) h1 -> relu -> a1 (bf16)
//   K4 agg2_w2  : gather+fma(dinv[s]) a1 -> y -> GEMV @W2 + b2 -> relu -> out
// ---------------------------------------------------------------------------

#define DIN 256
#define DH 128
#define BKT_SHIFT 9
#define BKT_SZ 512
#define NBKT_MAX 256
#define CAP 10240

typedef __attribute__((ext_vector_type(8))) short short8;
typedef __attribute__((ext_vector_type(4))) float f32x4;
typedef __attribute__((ext_vector_type(2))) float f32x2;
typedef __attribute__((ext_vector_type(2))) unsigned int uint2e;

__device__ __forceinline__ unsigned short f2bf(float f) {
    union { float f; unsigned int i; } c;
    c.f = f;
    unsigned int r = c.i + 0x7FFFu + ((c.i >> 16) & 1u);  // RNE
    return (unsigned short)(r >> 16);
}
__device__ __forceinline__ float bf_lo(unsigned int u) {
    union { unsigned int i; float f; } c;
    c.i = u << 16;
    return c.f;
}
__device__ __forceinline__ float bf_hi(unsigned int u) {
    union { unsigned int i; float f; } c;
    c.i = u & 0xFFFF0000u;
    return c.f;
}

// ---------------- K0: W1 conversion + zero bcnt -----------------------------
__global__ __launch_bounds__(256) void cvt_zero_k(const float* __restrict__ W1,
                                                  unsigned short* __restrict__ Wt1,
                                                  int* __restrict__ bcnt, int WTB) {
    int bx = blockIdx.x;
    int t = threadIdx.x;
    if (bx >= WTB) {
        bcnt[t] = 0;
        return;
    }
    int i = bx * 256 + t;  // i < 256*128
    int k = i >> 7, nn = i & 127;
    Wt1[(size_t)nn * 256 + k] = f2bf(W1[i]);
}

// ---------------- GEMM body (MFMA bf16) -------------------------------------
// G[M,128] = A[M,K] @ Wt^T, bf16 out (unscaled). Wt is [128][K] bf16.
// Bt LDS layout is fragment-major (stride-1 b128 reads, conflict-free).
__device__ __forceinline__ void gemm_body(unsigned short* Bt, int gb,
                                          const float* __restrict__ Af,
                                          const unsigned short* __restrict__ Wt,
                                          unsigned short* __restrict__ Hb,
                                          int M, int K) {
    const int t = threadIdx.x;
    const int w = t >> 6;
    const int lane = t & 63;
    const int l15 = lane & 15;
    const int quad = lane >> 4;
    const int row0 = gb * 128 + w * 32;

    f32x4 acc[2][8];
#pragma unroll
    for (int rt = 0; rt < 2; ++rt)
#pragma unroll
        for (int ct = 0; ct < 8; ++ct)
#pragma unroll
            for (int j = 0; j < 4; ++j) acc[rt][ct][j] = 0.0f;

    for (int kc = 0; kc < K; kc += 128) {
        if (kc) __syncthreads();
#pragma unroll
        for (int i = 0; i < 8; ++i) {
            int fg = w * 8 + i;
            int ks = fg >> 3, ct = fg & 7;
            int nn = ct * 16 + l15;
            int gk = ks * 32 + quad * 8;
            *(short8*)&Bt[fg * 512 + lane * 8] =
                *(const short8*)(Wt + (size_t)nn * K + kc + gk);
        }
        __syncthreads();
#pragma unroll
        for (int ks = 0; ks < 4; ++ks) {
            int kk = ks * 32 + quad * 8;
            short8 af[2];
#pragma unroll
            for (int rt = 0; rt < 2; ++rt) {
                int row = row0 + rt * 16 + l15;
                if (row < M) {
                    const float* p = Af + (size_t)row * K + kc + kk;
                    float4 x0 = *(const float4*)p;
                    float4 x1 = *(const float4*)(p + 4);
                    af[rt][0] = (short)f2bf(x0.x);
                    af[rt][1] = (short)f2bf(x0.y);
                    af[rt][2] = (short)f2bf(x0.z);
                    af[rt][3] = (short)f2bf(x0.w);
                    af[rt][4] = (short)f2bf(x1.x);
                    af[rt][5] = (short)f2bf(x1.y);
                    af[rt][6] = (short)f2bf(x1.z);
                    af[rt][7] = (short)f2bf(x1.w);
                } else {
#pragma unroll
                    for (int j = 0; j < 8; ++j) af[rt][j] = 0;
                }
            }
#pragma unroll
            for (int ct = 0; ct < 8; ++ct) {
                short8 bfr = *(const short8*)&Bt[(ks * 8 + ct) * 512 + lane * 8];
                acc[0][ct] = __builtin_amdgcn_mfma_f32_16x16x32_bf16(af[0], bfr, acc[0][ct], 0, 0, 0);
                acc[1][ct] = __builtin_amdgcn_mfma_f32_16x16x32_bf16(af[1], bfr, acc[1][ct], 0, 0, 0);
            }
        }
    }
#pragma unroll
    for (int rt = 0; rt < 2; ++rt)
#pragma unroll
        for (int r = 0; r < 4; ++r) {
            int row = row0 + rt * 16 + quad * 4 + r;
            if (row < M) {
                unsigned short* o = Hb + (size_t)row * 128 + l15;
#pragma unroll
                for (int ct = 0; ct < 8; ++ct) o[ct * 16] = f2bf(acc[rt][ct][r]);
            }
        }
}

// ---------------- K1: fused bucket-binning + gemm1 --------------------------
// record: src | (dlow9 << 20)  (src < 2^17)
struct SmemFused {
    union {
        unsigned short Bt[16384];
        struct {
            int hist[NBKT_MAX];
            int rstart[NBKT_MAX];
        } bk;
    };
};

__global__ __launch_bounds__(256) void fused1_k(const int* __restrict__ src,
                                                const int* __restrict__ dst,
                                                int* __restrict__ bcnt,
                                                int* __restrict__ tmp, int e, int n,
                                                int NBB,
                                                const float* __restrict__ x,
                                                const unsigned short* __restrict__ Wt1,
                                                unsigned short* __restrict__ hb, int M) {
    __shared__ SmemFused sm;
    int bx = blockIdx.x;
    int t = threadIdx.x;
    if (bx < NBB) {
        int* hist = sm.bk.hist;
        int* rstart = sm.bk.rstart;
        int chunk = (e + NBB - 1) / NBB;
        int beg = bx * chunk, end = min(e, beg + chunk);

        hist[t] = 0;
        __syncthreads();
        for (int i = beg + t; i < end; i += 256) atomicAdd(&hist[dst[i] >> BKT_SHIFT], 1);
        __syncthreads();
        int nbkt = (n + BKT_SZ - 1) >> BKT_SHIFT;
        int h = hist[t];
        if (t < nbkt && h > 0) rstart[t] = atomicAdd(&bcnt[t], h);
        __syncthreads();
        hist[t] = 0;
        __syncthreads();
        for (int i = beg + t; i < end; i += 256) {
            int d = dst[i];
            int b = d >> BKT_SHIFT;
            int o = atomicAdd(&hist[b], 1);
            tmp[(size_t)b * CAP + rstart[b] + o] = src[i] | ((d & (BKT_SZ - 1)) << 20);
        }
        return;
    }
    // gemm1: unscaled h1 = bf16(x @ W1^T)
    gemm_body(sm.Bt, bx - NBB, x, Wt1, hb, M, DIN);
}

// ---------------- K2: per-bucket scan + deg->dinv + scatter -----------------
__global__ __launch_bounds__(1024) void scatter2_k(const int* __restrict__ tmp,
                                                   const int* __restrict__ bcnt,
                                                   float* __restrict__ dinv,
                                                   int* __restrict__ rowptr,
                                                   int* __restrict__ einfo, int n,
                                                   int nbkt) {
    __shared__ int hist[BKT_SZ];
    __shared__ int scn[BKT_SZ];
    __shared__ int cur[BKT_SZ];
    int b = blockIdx.x;
    int t = threadIdx.x;
    int lo = b << BKT_SHIFT;
    int nn = min(n - lo, BKT_SZ);
    int cnt = bcnt[b];
    const int* rec = tmp + (size_t)b * CAP;

    // inline exclusive scan of bcnt[0..nbkt) -> bas
    if (t < 256) scn[t] = (t < nbkt) ? bcnt[t] : 0;
    __syncthreads();
    for (int off = 1; off < 256; off <<= 1) {
        int v = 0;
        if (t < 256 && t >= off) v = scn[t - off];
        __syncthreads();
        if (t < 256) scn[t] += v;
        __syncthreads();
    }
    int bas = scn[b] - cnt;  // exclusive prefix of this bucket
    if (b == nbkt - 1 && t == 0) rowptr[n] = scn[nbkt - 1];  // == E
    __syncthreads();

    if (t < BKT_SZ) hist[t] = 0;
    __syncthreads();
    for (int i = t; i < cnt; i += 1024) atomicAdd(&hist[(rec[i] >> 20) & (BKT_SZ - 1)], 1);
    __syncthreads();
    if (t < BKT_SZ) scn[t] = hist[t];
    __syncthreads();
    for (int off = 1; off < BKT_SZ; off <<= 1) {
        int v = 0;
        if (t < BKT_SZ && t >= off) v = scn[t - off];
        __syncthreads();
        if (t < BKT_SZ) scn[t] += v;
        __syncthreads();
    }
    if (t < nn) {
        int excl = bas + scn[t] - hist[t];
        dinv[lo + t] = 1.0f / sqrtf((float)(hist[t] + 1));
        rowptr[lo + t] = excl;
        cur[t] = excl;
    }
    __syncthreads();
    for (int i = t; i < cnt; i += 1024) {
        int r = rec[i];
        int dlow = (r >> 20) & (BKT_SZ - 1);
        int pos = atomicAdd(&cur[dlow], 1);
        einfo[pos] = r & 0xFFFFF;
    }
}

// ---------------- gather core (dinv[s]-weighted, 8-deep) --------------------
// Accumulates a0..a3 = dims {4l..4l+3} of sum_s dinv[s]*H[s] (+ self term),
// per half-wave; after shfl_xor(32) reduce, BOTH halves hold the full sums.
__device__ __forceinline__ void gather_scaled(const uint2* __restrict__ H,
                                              const int* __restrict__ rowptr,
                                              const int* __restrict__ einfo,
                                              const float* __restrict__ dinv,
                                              int v, int l, int half, float dv,
                                              float& a0, float& a1, float& a2, float& a3) {
    if (half == 0) {
        uint2 hv = H[(size_t)v * 32 + l];  // self-loop term
        a0 = dv * bf_lo(hv.x); a1 = dv * bf_hi(hv.x);
        a2 = dv * bf_lo(hv.y); a3 = dv * bf_hi(hv.y);
    }
    int end = rowptr[v + 1];
    int i = rowptr[v] + half;
    for (; i + 14 < end; i += 16) {
        int s0 = __builtin_nontemporal_load(&einfo[i]);
        int s1 = __builtin_nontemporal_load(&einfo[i + 2]);
        int s2 = __builtin_nontemporal_load(&einfo[i + 4]);
        int s3 = __builtin_nontemporal_load(&einfo[i + 6]);
        int s4 = __builtin_nontemporal_load(&einfo[i + 8]);
        int s5 = __builtin_nontemporal_load(&einfo[i + 10]);
        int s6 = __builtin_nontemporal_load(&einfo[i + 12]);
        int s7 = __builtin_nontemporal_load(&einfo[i + 14]);
        float d0 = dinv[s0], d1 = dinv[s1], d2 = dinv[s2], d3 = dinv[s3];
        float d4 = dinv[s4], d5 = dinv[s5], d6 = dinv[s6], d7 = dinv[s7];
        uint2 v0 = H[(size_t)s0 * 32 + l];
        uint2 v1 = H[(size_t)s1 * 32 + l];
        uint2 v2 = H[(size_t)s2 * 32 + l];
        uint2 v3 = H[(size_t)s3 * 32 + l];
        uint2 v4 = H[(size_t)s4 * 32 + l];
        uint2 v5 = H[(size_t)s5 * 32 + l];
        uint2 v6 = H[(size_t)s6 * 32 + l];
        uint2 v7 = H[(size_t)s7 * 32 + l];
        a0 = fmaf(d0, bf_lo(v0.x), a0); a1 = fmaf(d0, bf_hi(v0.x), a1);
        a2 = fmaf(d0, bf_lo(v0.y), a2); a3 = fmaf(d0, bf_hi(v0.y), a3);
        a0 = fmaf(d1, bf_lo(v1.x), a0); a1 = fmaf(d1, bf_hi(v1.x), a1);
        a2 = fmaf(d1, bf_lo(v1.y), a2); a3 = fmaf(d1, bf_hi(v1.y), a3);
        a0 = fmaf(d2, bf_lo(v2.x), a0); a1 = fmaf(d2, bf_hi(v2.x), a1);
        a2 = fmaf(d2, bf_lo(v2.y), a2); a3 = fmaf(d2, bf_hi(v2.y), a3);
        a0 = fmaf(d3, bf_lo(v3.x), a0); a1 = fmaf(d3, bf_hi(v3.x), a1);
        a2 = fmaf(d3, bf_lo(v3.y), a2); a3 = fmaf(d3, bf_hi(v3.y), a3);
        a0 = fmaf(d4, bf_lo(v4.x), a0); a1 = fmaf(d4, bf_hi(v4.x), a1);
        a2 = fmaf(d4, bf_lo(v4.y), a2); a3 = fmaf(d4, bf_hi(v4.y), a3);
        a0 = fmaf(d5, bf_lo(v5.x), a0); a1 = fmaf(d5, bf_hi(v5.x), a1);
        a2 = fmaf(d5, bf_lo(v5.y), a2); a3 = fmaf(d5, bf_hi(v5.y), a3);
        a0 = fmaf(d6, bf_lo(v6.x), a0); a1 = fmaf(d6, bf_hi(v6.x), a1);
        a2 = fmaf(d6, bf_lo(v6.y), a2); a3 = fmaf(d6, bf_hi(v6.y), a3);
        a0 = fmaf(d7, bf_lo(v7.x), a0); a1 = fmaf(d7, bf_hi(v7.x), a1);
        a2 = fmaf(d7, bf_lo(v7.y), a2); a3 = fmaf(d7, bf_hi(v7.y), a3);
    }
    for (; i + 6 < end; i += 8) {
        int s0 = __builtin_nontemporal_load(&einfo[i]);
        int s1 = __builtin_nontemporal_load(&einfo[i + 2]);
        int s2 = __builtin_nontemporal_load(&einfo[i + 4]);
        int s3 = __builtin_nontemporal_load(&einfo[i + 6]);
        float d0 = dinv[s0], d1 = dinv[s1], d2 = dinv[s2], d3 = dinv[s3];
        uint2 v0 = H[(size_t)s0 * 32 + l];
        uint2 v1 = H[(size_t)s1 * 32 + l];
        uint2 v2 = H[(size_t)s2 * 32 + l];
        uint2 v3 = H[(size_t)s3 * 32 + l];
        a0 = fmaf(d0, bf_lo(v0.x), a0); a1 = fmaf(d0, bf_hi(v0.x), a1);
        a2 = fmaf(d0, bf_lo(v0.y), a2); a3 = fmaf(d0, bf_hi(v0.y), a3);
        a0 = fmaf(d1, bf_lo(v1.x), a0); a1 = fmaf(d1, bf_hi(v1.x), a1);
        a2 = fmaf(d1, bf_lo(v1.y), a2); a3 = fmaf(d1, bf_hi(v1.y), a3);
        a0 = fmaf(d2, bf_lo(v2.x), a0); a1 = fmaf(d2, bf_hi(v2.x), a1);
        a2 = fmaf(d2, bf_lo(v2.y), a2); a3 = fmaf(d2, bf_hi(v2.y), a3);
        a0 = fmaf(d3, bf_lo(v3.x), a0); a1 = fmaf(d3, bf_hi(v3.x), a1);
        a2 = fmaf(d3, bf_lo(v3.y), a2); a3 = fmaf(d3, bf_hi(v3.y), a3);
    }
    for (; i < end; i += 2) {
        int s = __builtin_nontemporal_load(&einfo[i]);
        float ds = dinv[s];
        uint2 vv = H[(size_t)s * 32 + l];
        a0 = fmaf(ds, bf_lo(vv.x), a0); a1 = fmaf(ds, bf_hi(vv.x), a1);
        a2 = fmaf(ds, bf_lo(vv.y), a2); a3 = fmaf(ds, bf_hi(vv.y), a3);
    }
    a0 += __shfl_xor(a0, 32);
    a1 += __shfl_xor(a1, 32);
    a2 += __shfl_xor(a2, 32);
    a3 += __shfl_xor(a3, 32);
}

// ---------------- K3: agg1 (gather h1 -> relu -> a1 bf16) -------------------
__global__ __launch_bounds__(256, 8) void agg1_k(const unsigned short* __restrict__ Hb,
                                                 const int* __restrict__ rowptr,
                                                 const int* __restrict__ einfo,
                                                 const float* __restrict__ dinv,
                                                 const float* __restrict__ bias,
                                                 unsigned short* __restrict__ out, int n) {
    int v = blockIdx.x * 4 + (threadIdx.x >> 6);
    int lane = threadIdx.x & 63;
    if (v >= n) return;
    int l = lane & 31, half = lane >> 5;
    float dv = dinv[v];
    float a0 = 0.f, a1 = 0.f, a2 = 0.f, a3 = 0.f;
    gather_scaled((const uint2*)Hb, rowptr, einfo, dinv, v, l, half, dv, a0, a1, a2, a3);
    if (half == 0) {
        float4 bb = ((const float4*)bias)[l];
        float o0 = fmaxf(fmaf(dv, a0, bb.x), 0.f);
        float o1 = fmaxf(fmaf(dv, a1, bb.y), 0.f);
        float o2 = fmaxf(fmaf(dv, a2, bb.z), 0.f);
        float o3 = fmaxf(fmaf(dv, a3, bb.w), 0.f);
        uint2e p;
        p.x = (unsigned int)f2bf(o0) | ((unsigned int)f2bf(o1) << 16);
        p.y = (unsigned int)f2bf(o2) | ((unsigned int)f2bf(o3) << 16);
        __builtin_nontemporal_store(p, (uint2e*)out + (size_t)v * 32 + l);
    }
}

// ---------------- K4: agg2 + distributive W2 GEMV ---------------------------
// y[v] = dinv[v]*(sum_s dinv[s]*a1[s] + dinv[v]*a1[v])   (gather, as agg1)
// out[v] = relu(y[v] @ W2 + b2)                          (per-wave GEMV)
// After the xor-32 reduce all 64 lanes hold full y (dims 4*(lane&31)+{0..3});
// lane computes output dims {2*lane, 2*lane+1}: 32 quad-broadcast shfls +
// 256 fma; W2 f32 [128][128] row slices are L2-hot (64KB total).
__global__ __launch_bounds__(256, 8) void agg2_w2_k(const unsigned short* __restrict__ A,
                                                    const int* __restrict__ rowptr,
                                                    const int* __restrict__ einfo,
                                                    const float* __restrict__ dinv,
                                                    const float* __restrict__ W2,
                                                    const float* __restrict__ b2,
                                                    float* __restrict__ out, int n) {
    int v = blockIdx.x * 4 + (threadIdx.x >> 6);
    int lane = threadIdx.x & 63;
    if (v >= n) return;
    int l = lane & 31, half = lane >> 5;
    float dv = dinv[v];
    float a0 = 0.f, a1 = 0.f, a2 = 0.f, a3 = 0.f;
    gather_scaled((const uint2*)A, rowptr, einfo, dinv, v, l, half, dv, a0, a1, a2, a3);
    // y = dv * sum (all 64 lanes have the full reduction)
    a0 *= dv; a1 *= dv; a2 *= dv; a3 *= dv;
    // GEMV: out dims c0=2*lane, c1=2*lane+1
    float o0 = b2[2 * lane];
    float o1 = b2[2 * lane + 1];
#pragma unroll 4
    for (int kq = 0; kq < 32; ++kq) {
        float y0 = __shfl(a0, kq);
        float y1 = __shfl(a1, kq);
        float y2 = __shfl(a2, kq);
        float y3 = __shfl(a3, kq);
        const float* wr = W2 + (size_t)(4 * kq) * 128 + 2 * lane;
        f32x2 w0 = *(const f32x2*)(wr);
        f32x2 w1 = *(const f32x2*)(wr + 128);
        f32x2 w2 = *(const f32x2*)(wr + 256);
        f32x2 w3 = *(const f32x2*)(wr + 384);
        o0 = fmaf(y0, w0.x, o0); o1 = fmaf(y0, w0.y, o1);
        o0 = fmaf(y1, w1.x, o0); o1 = fmaf(y1, w1.y, o1);
        o0 = fmaf(y2, w2.x, o0); o1 = fmaf(y2, w2.y, o1);
        o0 = fmaf(y3, w3.x, o0); o1 = fmaf(y3, w3.y, o1);
    }
    o0 = fmaxf(o0, 0.f);
    o1 = fmaxf(o1, 0.f);
    f32x2 ov = {o0, o1};
    __builtin_nontemporal_store(ov, (f32x2*)(out + (size_t)v * 128) + lane);
}

static inline size_t align_up(size_t x, size_t a) { return (x + a - 1) & ~(a - 1); }

extern "C" void kernel_launch(void* const* d_in, const int* in_sizes, int n_in,
                              void* d_out, int out_size, void* d_ws, size_t ws_size,
                              hipStream_t stream) {
    const float* x  = (const float*)d_in[0];
    const int*   ei = (const int*)d_in[1];
    const float* W1 = (const float*)d_in[2];
    const float* b1 = (const float*)d_in[3];
    const float* W2 = (const float*)d_in[4];
    const float* b2 = (const float*)d_in[5];

    const int N = in_sizes[0] / DIN;   // 100000
    const int E = in_sizes[1] / 2;     // 1600000
    const int* src = ei;
    const int* dst = ei + E;
    const int NBKT = (N + BKT_SZ - 1) >> BKT_SHIFT;  // 196

    // workspace partition
    char* base_p = (char*)d_ws;
    size_t off = 0;
    int* bcnt = (int*)(base_p + off);       off = align_up(off + 256 * 4, 256);
    int* rowptr = (int*)(base_p + off);     off = align_up(off + (size_t)(N + 1) * 4, 256);
    float* dinv = (float*)(base_p + off);   off = align_up(off + (size_t)N * 4, 256);
    int* tmp = (int*)(base_p + off);        off = align_up(off + (size_t)NBKT * CAP * 4, 256);
    int* einfo = (int*)(base_p + off);      off = align_up(off + (size_t)E * 4, 256);
    unsigned short* Wt1 = (unsigned short*)(base_p + off); off = align_up(off + (size_t)128 * 256 * 2, 256);
    unsigned short* hb  = (unsigned short*)(base_p + off); off = align_up(off + (size_t)N * 128 * 2, 256);
    unsigned short* a1b = (unsigned short*)(base_p + off); off = align_up(off + (size_t)N * 128 * 2, 256);

    float* out = (float*)d_out;

    const int NBB = 512;                    // bucket blocks
    const int WTB = (256 * 128) / 256;      // 128 W1-convert blocks
    const int GB = (N + 127) / 128;         // 782 gemm blocks

    // K0: W1 cvt + zero bcnt
    cvt_zero_k<<<WTB + 1, 256, 0, stream>>>(W1, Wt1, bcnt, WTB);
    // K1: bucket-binning || gemm1 (unscaled) in one kernel
    fused1_k<<<NBB + GB, 256, 0, stream>>>(src, dst, bcnt, tmp, E, N, NBB, x, Wt1, hb, N);
    // K2: per-bucket scan (inline 196-prefix) + dinv + rowptr + einfo scatter
    scatter2_k<<<NBKT, 1024, 0, stream>>>(tmp, bcnt, dinv, rowptr, einfo, N, NBKT);
    // K3: agg1 -> a1 (bf16)
    agg1_k<<<(N + 3) / 4, 256, 0, stream>>>(hb, rowptr, einfo, dinv, b1, a1b, N);
    // K4: agg2 + W2 GEMV epilogue -> fp32 out (gemm2 deleted via distributivity)
    agg2_w2_k<<<(N + 3) / 4, 256, 0, stream>>>(a1b, rowptr, einfo, dinv, W2, b2, out, N);
}

// Round 9
// 408.952 us; speedup vs baseline: 1.7723x; 1.7723x over previous
//
#include <hip/hip_runtime.h>
#include <hip/hip_bf16.h>

// ---------------------------------------------------------------------------
// GCN 2-layer forward on MI355X (gfx950). BEST VERIFIED CONFIG (R6: 408.7us).
// Accounting (R4 probes + R1/R5/R6 deltas): aggs 2x85us at the random-gather
// DRAM floor (FETCH = 8 XCD x 25.6MB compulsory; 2.7 TB/s invariant to gather
// depth 4 vs 8; zero bank conflicts; occupancy 72%); middle ~70us (gemm1 ~30
// overlapped with binning, gemm2 21 MFMA, scatter2+cvt ~12); ~170us fixed
// harness-reset mass. Structural alternatives all measured worse:
//   R2  fuse gemm2 into agg1 via MFMA epilogue: +78us (barrier coupling)
//   R5  global atomic scatter: +133us (16x write amplification)
//   R8  fuse gemm2 into agg2 via per-wave GEMV: +365us (zero W2 reuse,
//       6.4GB L2 traffic + 128 serial bpermutes per wave)
// Pipeline (6 launches):
//   K0 cvt_zero : weight f32->bf16 transpose + zero bcnt   (193 blocks)
//   K1 fused1   : blocks [0,NBB) bucket-bin edges; blocks [NBB,..) gemm1
//   K2 scatter2 : inline 196-scan of bcnt; deg->dinv; rowptr; einfo
//   K3 agg1     : gather+fma(dinv[s]) -> relu -> a1 (bf16)
//   K4 gemm2    : g2 = dinv*(a1@W2), bf16
//   K5 agg2     : gather-add of g2 -> relu -> out (fp32)
// ---------------------------------------------------------------------------

#define DIN 256
#define DH 128
#define BKT_SHIFT 9
#define BKT_SZ 512
#define NBKT_MAX 256
#define CAP 10240

typedef __attribute__((ext_vector_type(8))) short short8;
typedef __attribute__((ext_vector_type(4))) float f32x4;
typedef __attribute__((ext_vector_type(2))) unsigned int uint2e;

__device__ __forceinline__ unsigned short f2bf(float f) {
    union { float f; unsigned int i; } c;
    c.f = f;
    unsigned int r = c.i + 0x7FFFu + ((c.i >> 16) & 1u);  // RNE
    return (unsigned short)(r >> 16);
}
__device__ __forceinline__ float bf_lo(unsigned int u) {
    union { unsigned int i; float f; } c;
    c.i = u << 16;
    return c.f;
}
__device__ __forceinline__ float bf_hi(unsigned int u) {
    union { unsigned int i; float f; } c;
    c.i = u & 0xFFFF0000u;
    return c.f;
}

// ---------------- K0: weight conversion + zero bcnt -------------------------
__global__ __launch_bounds__(256) void cvt_zero_k(const float* __restrict__ W1,
                                                  const float* __restrict__ W2,
                                                  unsigned short* __restrict__ Wt1,
                                                  unsigned short* __restrict__ Wt2,
                                                  int* __restrict__ bcnt, int WTB) {
    int bx = blockIdx.x;
    int t = threadIdx.x;
    if (bx >= WTB) {
        bcnt[t] = 0;
        return;
    }
    int i = bx * 256 + t;
    if (i < 256 * 128) {
        int k = i >> 7, nn = i & 127;
        Wt1[(size_t)nn * 256 + k] = f2bf(W1[i]);
    } else {
        int j = i - 256 * 128;
        int k = j >> 7, nn = j & 127;
        Wt2[(size_t)nn * 128 + k] = f2bf(W2[j]);
    }
}

// ---------------- GEMM body (MFMA bf16) -------------------------------------
// G[M,128] = (SCALE ? dinv[row] : 1) * (A[M,K] @ Wt^T), bf16 out.
// Wt is [128][K] bf16. Bt LDS layout is fragment-major (stride-1 b128 reads).
template <bool A_BF16, bool SCALE>
__device__ __forceinline__ void gemm_body(unsigned short* Bt, int gb,
                                          const void* __restrict__ Av,
                                          const unsigned short* __restrict__ Wt,
                                          const float* __restrict__ dinv,
                                          unsigned short* __restrict__ Hb,
                                          int M, int K) {
    const int t = threadIdx.x;
    const int w = t >> 6;
    const int lane = t & 63;
    const int l15 = lane & 15;
    const int quad = lane >> 4;
    const int row0 = gb * 128 + w * 32;

    const float* Af = (const float*)Av;
    const unsigned short* Ab = (const unsigned short*)Av;

    f32x4 acc[2][8];
#pragma unroll
    for (int rt = 0; rt < 2; ++rt)
#pragma unroll
        for (int ct = 0; ct < 8; ++ct)
#pragma unroll
            for (int j = 0; j < 4; ++j) acc[rt][ct][j] = 0.0f;

    for (int kc = 0; kc < K; kc += 128) {
        if (kc) __syncthreads();
#pragma unroll
        for (int i = 0; i < 8; ++i) {
            int fg = w * 8 + i;
            int ks = fg >> 3, ct = fg & 7;
            int nn = ct * 16 + l15;
            int gk = ks * 32 + quad * 8;
            *(short8*)&Bt[fg * 512 + lane * 8] =
                *(const short8*)(Wt + (size_t)nn * K + kc + gk);
        }
        __syncthreads();
#pragma unroll
        for (int ks = 0; ks < 4; ++ks) {
            int kk = ks * 32 + quad * 8;
            short8 af[2];
#pragma unroll
            for (int rt = 0; rt < 2; ++rt) {
                int row = row0 + rt * 16 + l15;
                if (row < M) {
                    if (A_BF16) {
                        af[rt] = *(const short8*)(Ab + (size_t)row * K + kc + kk);
                    } else {
                        const float* p = Af + (size_t)row * K + kc + kk;
                        float4 x0 = *(const float4*)p;
                        float4 x1 = *(const float4*)(p + 4);
                        af[rt][0] = (short)f2bf(x0.x);
                        af[rt][1] = (short)f2bf(x0.y);
                        af[rt][2] = (short)f2bf(x0.z);
                        af[rt][3] = (short)f2bf(x0.w);
                        af[rt][4] = (short)f2bf(x1.x);
                        af[rt][5] = (short)f2bf(x1.y);
                        af[rt][6] = (short)f2bf(x1.z);
                        af[rt][7] = (short)f2bf(x1.w);
                    }
                } else {
#pragma unroll
                    for (int j = 0; j < 8; ++j) af[rt][j] = 0;
                }
            }
#pragma unroll
            for (int ct = 0; ct < 8; ++ct) {
                short8 bfr = *(const short8*)&Bt[(ks * 8 + ct) * 512 + lane * 8];
                acc[0][ct] = __builtin_amdgcn_mfma_f32_16x16x32_bf16(af[0], bfr, acc[0][ct], 0, 0, 0);
                acc[1][ct] = __builtin_amdgcn_mfma_f32_16x16x32_bf16(af[1], bfr, acc[1][ct], 0, 0, 0);
            }
        }
    }
#pragma unroll
    for (int rt = 0; rt < 2; ++rt)
#pragma unroll
        for (int r = 0; r < 4; ++r) {
            int row = row0 + rt * 16 + quad * 4 + r;
            if (row < M) {
                float dv = SCALE ? dinv[row] : 1.0f;
                unsigned short* o = Hb + (size_t)row * 128 + l15;
#pragma unroll
                for (int ct = 0; ct < 8; ++ct)
                    o[ct * 16] = f2bf(SCALE ? dv * acc[rt][ct][r] : acc[rt][ct][r]);
            }
        }
}

// ---------------- K1: fused bucket-binning + gemm1 --------------------------
// record: src | (dlow9 << 20)  (src < 2^17)
struct SmemFused {
    union {
        unsigned short Bt[16384];
        struct {
            int hist[NBKT_MAX];
            int rstart[NBKT_MAX];
        } bk;
    };
};

__global__ __launch_bounds__(256) void fused1_k(const int* __restrict__ src,
                                                const int* __restrict__ dst,
                                                int* __restrict__ bcnt,
                                                int* __restrict__ tmp, int e, int n,
                                                int NBB,
                                                const float* __restrict__ x,
                                                const unsigned short* __restrict__ Wt1,
                                                unsigned short* __restrict__ hb, int M) {
    __shared__ SmemFused sm;
    int bx = blockIdx.x;
    int t = threadIdx.x;
    if (bx < NBB) {
        int* hist = sm.bk.hist;
        int* rstart = sm.bk.rstart;
        int chunk = (e + NBB - 1) / NBB;
        int beg = bx * chunk, end = min(e, beg + chunk);

        hist[t] = 0;
        __syncthreads();
        for (int i = beg + t; i < end; i += 256) atomicAdd(&hist[dst[i] >> BKT_SHIFT], 1);
        __syncthreads();
        int nbkt = (n + BKT_SZ - 1) >> BKT_SHIFT;
        int h = hist[t];
        if (t < nbkt && h > 0) rstart[t] = atomicAdd(&bcnt[t], h);
        __syncthreads();
        hist[t] = 0;
        __syncthreads();
        for (int i = beg + t; i < end; i += 256) {
            int d = dst[i];
            int b = d >> BKT_SHIFT;
            int o = atomicAdd(&hist[b], 1);
            tmp[(size_t)b * CAP + rstart[b] + o] = src[i] | ((d & (BKT_SZ - 1)) << 20);
        }
        return;
    }
    // gemm1: unscaled h1 = bf16(x @ W1^T)
    gemm_body<false, false>(sm.Bt, bx - NBB, x, Wt1, nullptr, hb, M, DIN);
}

// ---------------- K2: per-bucket scan + deg->dinv + scatter -----------------
__global__ __launch_bounds__(1024) void scatter2_k(const int* __restrict__ tmp,
                                                   const int* __restrict__ bcnt,
                                                   float* __restrict__ dinv,
                                                   int* __restrict__ rowptr,
                                                   int* __restrict__ einfo, int n,
                                                   int nbkt) {
    __shared__ int hist[BKT_SZ];
    __shared__ int scn[BKT_SZ];
    __shared__ int cur[BKT_SZ];
    int b = blockIdx.x;
    int t = threadIdx.x;
    int lo = b << BKT_SHIFT;
    int nn = min(n - lo, BKT_SZ);
    int cnt = bcnt[b];
    const int* rec = tmp + (size_t)b * CAP;

    // inline exclusive scan of bcnt[0..nbkt) -> bas
    if (t < 256) scn[t] = (t < nbkt) ? bcnt[t] : 0;
    __syncthreads();
    for (int off = 1; off < 256; off <<= 1) {
        int v = 0;
        if (t < 256 && t >= off) v = scn[t - off];
        __syncthreads();
        if (t < 256) scn[t] += v;
        __syncthreads();
    }
    int bas = scn[b] - cnt;  // exclusive prefix of this bucket
    if (b == nbkt - 1 && t == 0) rowptr[n] = scn[nbkt - 1];  // == E
    __syncthreads();

    if (t < BKT_SZ) hist[t] = 0;
    __syncthreads();
    for (int i = t; i < cnt; i += 1024) atomicAdd(&hist[(rec[i] >> 20) & (BKT_SZ - 1)], 1);
    __syncthreads();
    if (t < BKT_SZ) scn[t] = hist[t];
    __syncthreads();
    for (int off = 1; off < BKT_SZ; off <<= 1) {
        int v = 0;
        if (t < BKT_SZ && t >= off) v = scn[t - off];
        __syncthreads();
        if (t < BKT_SZ) scn[t] += v;
        __syncthreads();
    }
    if (t < nn) {
        int excl = bas + scn[t] - hist[t];
        dinv[lo + t] = 1.0f / sqrtf((float)(hist[t] + 1));
        rowptr[lo + t] = excl;
        cur[t] = excl;
    }
    __syncthreads();
    for (int i = t; i < cnt; i += 1024) {
        int r = rec[i];
        int dlow = (r >> 20) & (BKT_SZ - 1);
        int pos = atomicAdd(&cur[dlow], 1);
        einfo[pos] = r & 0xFFFFF;
    }
}

// ---------------- aggregation ----------------
// SCALE_SRC: out[v] = relu(dinv[v]*(sum dinv[s]*h[s] + dinv[v]*h[v]) + b)
// else:      out[v] = relu(dinv[v]*(sum g[s] + g[v]) + b)   (g pre-scaled)
// 1 wave/node; half-wave per 256B bf16 row (uint2/lane); halves take even/odd
// edges; 8 gathers in flight per half (R6: rate identical to 4-deep -> at the
// random-gather DRAM floor, kept for the marginally better tail behavior).
template <bool SCALE_SRC, bool OUT_BF16>
__global__ __launch_bounds__(256, 8) void agg_k(const unsigned short* __restrict__ Hb,
                                                const int* __restrict__ rowptr,
                                                const int* __restrict__ einfo,
                                                const float* __restrict__ dinv,
                                                const float* __restrict__ bias,
                                                void* __restrict__ out, int n) {
    int v = blockIdx.x * 4 + (threadIdx.x >> 6);
    int lane = threadIdx.x & 63;
    if (v >= n) return;
    int l = lane & 31, half = lane >> 5;
    const uint2* __restrict__ H = (const uint2*)Hb;  // row = 32 x uint2
    float dv = dinv[v];
    float a0 = 0.f, a1 = 0.f, a2 = 0.f, a3 = 0.f;
    if (half == 0) {
        uint2 hv = H[(size_t)v * 32 + l];  // self-loop term
        if (SCALE_SRC) {
            a0 = dv * bf_lo(hv.x); a1 = dv * bf_hi(hv.x);
            a2 = dv * bf_lo(hv.y); a3 = dv * bf_hi(hv.y);
        } else {
            a0 = bf_lo(hv.x); a1 = bf_hi(hv.x);
            a2 = bf_lo(hv.y); a3 = bf_hi(hv.y);
        }
    }
    int end = rowptr[v + 1];
    int i = rowptr[v] + half;
    // -------- 8-deep batch --------
    for (; i + 14 < end; i += 16) {
        int s0 = __builtin_nontemporal_load(&einfo[i]);
        int s1 = __builtin_nontemporal_load(&einfo[i + 2]);
        int s2 = __builtin_nontemporal_load(&einfo[i + 4]);
        int s3 = __builtin_nontemporal_load(&einfo[i + 6]);
        int s4 = __builtin_nontemporal_load(&einfo[i + 8]);
        int s5 = __builtin_nontemporal_load(&einfo[i + 10]);
        int s6 = __builtin_nontemporal_load(&einfo[i + 12]);
        int s7 = __builtin_nontemporal_load(&einfo[i + 14]);
        float d0 = 1.f, d1 = 1.f, d2 = 1.f, d3 = 1.f;
        float d4 = 1.f, d5 = 1.f, d6 = 1.f, d7 = 1.f;
        if (SCALE_SRC) {
            d0 = dinv[s0]; d1 = dinv[s1]; d2 = dinv[s2]; d3 = dinv[s3];
            d4 = dinv[s4]; d5 = dinv[s5]; d6 = dinv[s6]; d7 = dinv[s7];
        }
        uint2 v0 = H[(size_t)s0 * 32 + l];
        uint2 v1 = H[(size_t)s1 * 32 + l];
        uint2 v2 = H[(size_t)s2 * 32 + l];
        uint2 v3 = H[(size_t)s3 * 32 + l];
        uint2 v4 = H[(size_t)s4 * 32 + l];
        uint2 v5 = H[(size_t)s5 * 32 + l];
        uint2 v6 = H[(size_t)s6 * 32 + l];
        uint2 v7 = H[(size_t)s7 * 32 + l];
        if (SCALE_SRC) {
            a0 = fmaf(d0, bf_lo(v0.x), a0); a1 = fmaf(d0, bf_hi(v0.x), a1);
            a2 = fmaf(d0, bf_lo(v0.y), a2); a3 = fmaf(d0, bf_hi(v0.y), a3);
            a0 = fmaf(d1, bf_lo(v1.x), a0); a1 = fmaf(d1, bf_hi(v1.x), a1);
            a2 = fmaf(d1, bf_lo(v1.y), a2); a3 = fmaf(d1, bf_hi(v1.y), a3);
            a0 = fmaf(d2, bf_lo(v2.x), a0); a1 = fmaf(d2, bf_hi(v2.x), a1);
            a2 = fmaf(d2, bf_lo(v2.y), a2); a3 = fmaf(d2, bf_hi(v2.y), a3);
            a0 = fmaf(d3, bf_lo(v3.x), a0); a1 = fmaf(d3, bf_hi(v3.x), a1);
            a2 = fmaf(d3, bf_lo(v3.y), a2); a3 = fmaf(d3, bf_hi(v3.y), a3);
            a0 = fmaf(d4, bf_lo(v4.x), a0); a1 = fmaf(d4, bf_hi(v4.x), a1);
            a2 = fmaf(d4, bf_lo(v4.y), a2); a3 = fmaf(d4, bf_hi(v4.y), a3);
            a0 = fmaf(d5, bf_lo(v5.x), a0); a1 = fmaf(d5, bf_hi(v5.x), a1);
            a2 = fmaf(d5, bf_lo(v5.y), a2); a3 = fmaf(d5, bf_hi(v5.y), a3);
            a0 = fmaf(d6, bf_lo(v6.x), a0); a1 = fmaf(d6, bf_hi(v6.x), a1);
            a2 = fmaf(d6, bf_lo(v6.y), a2); a3 = fmaf(d6, bf_hi(v6.y), a3);
            a0 = fmaf(d7, bf_lo(v7.x), a0); a1 = fmaf(d7, bf_hi(v7.x), a1);
            a2 = fmaf(d7, bf_lo(v7.y), a2); a3 = fmaf(d7, bf_hi(v7.y), a3);
        } else {
            a0 += bf_lo(v0.x); a1 += bf_hi(v0.x); a2 += bf_lo(v0.y); a3 += bf_hi(v0.y);
            a0 += bf_lo(v1.x); a1 += bf_hi(v1.x); a2 += bf_lo(v1.y); a3 += bf_hi(v1.y);
            a0 += bf_lo(v2.x); a1 += bf_hi(v2.x); a2 += bf_lo(v2.y); a3 += bf_hi(v2.y);
            a0 += bf_lo(v3.x); a1 += bf_hi(v3.x); a2 += bf_lo(v3.y); a3 += bf_hi(v3.y);
            a0 += bf_lo(v4.x); a1 += bf_hi(v4.x); a2 += bf_lo(v4.y); a3 += bf_hi(v4.y);
            a0 += bf_lo(v5.x); a1 += bf_hi(v5.x); a2 += bf_lo(v5.y); a3 += bf_hi(v5.y);
            a0 += bf_lo(v6.x); a1 += bf_hi(v6.x); a2 += bf_lo(v6.y); a3 += bf_hi(v6.y);
            a0 += bf_lo(v7.x); a1 += bf_hi(v7.x); a2 += bf_lo(v7.y); a3 += bf_hi(v7.y);
        }
    }
    // -------- 4-deep batch --------
    for (; i + 6 < end; i += 8) {
        int s0 = __builtin_nontemporal_load(&einfo[i]);
        int s1 = __builtin_nontemporal_load(&einfo[i + 2]);
        int s2 = __builtin_nontemporal_load(&einfo[i + 4]);
        int s3 = __builtin_nontemporal_load(&einfo[i + 6]);
        float d0 = 1.f, d1 = 1.f, d2 = 1.f, d3 = 1.f;
        if (SCALE_SRC) { d0 = dinv[s0]; d1 = dinv[s1]; d2 = dinv[s2]; d3 = dinv[s3]; }
        uint2 v0 = H[(size_t)s0 * 32 + l];
        uint2 v1 = H[(size_t)s1 * 32 + l];
        uint2 v2 = H[(size_t)s2 * 32 + l];
        uint2 v3 = H[(size_t)s3 * 32 + l];
        if (SCALE_SRC) {
            a0 = fmaf(d0, bf_lo(v0.x), a0); a1 = fmaf(d0, bf_hi(v0.x), a1);
            a2 = fmaf(d0, bf_lo(v0.y), a2); a3 = fmaf(d0, bf_hi(v0.y), a3);
            a0 = fmaf(d1, bf_lo(v1.x), a0); a1 = fmaf(d1, bf_hi(v1.x), a1);
            a2 = fmaf(d1, bf_lo(v1.y), a2); a3 = fmaf(d1, bf_hi(v1.y), a3);
            a0 = fmaf(d2, bf_lo(v2.x), a0); a1 = fmaf(d2, bf_hi(v2.x), a1);
            a2 = fmaf(d2, bf_lo(v2.y), a2); a3 = fmaf(d2, bf_hi(v2.y), a3);
            a0 = fmaf(d3, bf_lo(v3.x), a0); a1 = fmaf(d3, bf_hi(v3.x), a1);
            a2 = fmaf(d3, bf_lo(v3.y), a2); a3 = fmaf(d3, bf_hi(v3.y), a3);
        } else {
            a0 += bf_lo(v0.x); a1 += bf_hi(v0.x); a2 += bf_lo(v0.y); a3 += bf_hi(v0.y);
            a0 += bf_lo(v1.x); a1 += bf_hi(v1.x); a2 += bf_lo(v1.y); a3 += bf_hi(v1.y);
            a0 += bf_lo(v2.x); a1 += bf_hi(v2.x); a2 += bf_lo(v2.y); a3 += bf_hi(v2.y);
            a0 += bf_lo(v3.x); a1 += bf_hi(v3.x); a2 += bf_lo(v3.y); a3 += bf_hi(v3.y);
        }
    }
    for (; i < end; i += 2) {
        int s = __builtin_nontemporal_load(&einfo[i]);
        float ds = SCALE_SRC ? dinv[s] : 1.f;
        uint2 vv = H[(size_t)s * 32 + l];
        if (SCALE_SRC) {
            a0 = fmaf(ds, bf_lo(vv.x), a0); a1 = fmaf(ds, bf_hi(vv.x), a1);
            a2 = fmaf(ds, bf_lo(vv.y), a2); a3 = fmaf(ds, bf_hi(vv.y), a3);
        } else {
            a0 += bf_lo(vv.x); a1 += bf_hi(vv.x); a2 += bf_lo(vv.y); a3 += bf_hi(vv.y);
        }
    }
    a0 += __shfl_xor(a0, 32);
    a1 += __shfl_xor(a1, 32);
    a2 += __shfl_xor(a2, 32);
    a3 += __shfl_xor(a3, 32);
    if (half == 0) {
        float4 bb = ((const float4*)bias)[l];
        float o0 = fmaxf(fmaf(dv, a0, bb.x), 0.f);
        float o1 = fmaxf(fmaf(dv, a1, bb.y), 0.f);
        float o2 = fmaxf(fmaf(dv, a2, bb.z), 0.f);
        float o3 = fmaxf(fmaf(dv, a3, bb.w), 0.f);
        if (OUT_BF16) {
            uint2e p;
            p.x = (unsigned int)f2bf(o0) | ((unsigned int)f2bf(o1) << 16);
            p.y = (unsigned int)f2bf(o2) | ((unsigned int)f2bf(o3) << 16);
            __builtin_nontemporal_store(p, (uint2e*)out + (size_t)v * 32 + l);
        } else {
            f32x4 o = {o0, o1, o2, o3};
            __builtin_nontemporal_store(o, (f32x4*)out + (size_t)v * 32 + l);
        }
    }
}

// ---------------- K4: layer-2 GEMM ------------------------------------------
__global__ __launch_bounds__(256) void gemm2_k(const unsigned short* __restrict__ A,
                                               const unsigned short* __restrict__ Wt,
                                               const float* __restrict__ dinv,
                                               unsigned short* __restrict__ Hb,
                                               int M, int K) {
    __shared__ unsigned short Bt[16384];
    gemm_body<true, true>(Bt, blockIdx.x, A, Wt, dinv, Hb, M, K);
}

static inline size_t align_up(size_t x, size_t a) { return (x + a - 1) & ~(a - 1); }

extern "C" void kernel_launch(void* const* d_in, const int* in_sizes, int n_in,
                              void* d_out, int out_size, void* d_ws, size_t ws_size,
                              hipStream_t stream) {
    const float* x  = (const float*)d_in[0];
    const int*   ei = (const int*)d_in[1];
    const float* W1 = (const float*)d_in[2];
    const float* b1 = (const float*)d_in[3];
    const float* W2 = (const float*)d_in[4];
    const float* b2 = (const float*)d_in[5];

    const int N = in_sizes[0] / DIN;   // 100000
    const int E = in_sizes[1] / 2;     // 1600000
    const int* src = ei;
    const int* dst = ei + E;
    const int NBKT = (N + BKT_SZ - 1) >> BKT_SHIFT;  // 196

    // workspace partition
    char* base_p = (char*)d_ws;
    size_t off = 0;
    int* bcnt = (int*)(base_p + off);       off = align_up(off + 256 * 4, 256);
    int* rowptr = (int*)(base_p + off);     off = align_up(off + (size_t)(N + 1) * 4, 256);
    float* dinv = (float*)(base_p + off);   off = align_up(off + (size_t)N * 4, 256);
    int* tmp = (int*)(base_p + off);        off = align_up(off + (size_t)NBKT * CAP * 4, 256);
    int* einfo = (int*)(base_p + off);      off = align_up(off + (size_t)E * 4, 256);
    unsigned short* Wt1 = (unsigned short*)(base_p + off); off = align_up(off + (size_t)128 * 256 * 2, 256);
    unsigned short* Wt2 = (unsigned short*)(base_p + off); off = align_up(off + (size_t)128 * 128 * 2, 256);
    unsigned short* hb  = (unsigned short*)(base_p + off); off = align_up(off + (size_t)N * 128 * 2, 256);
    unsigned short* a1b = (unsigned short*)(base_p + off); off = align_up(off + (size_t)N * 128 * 2, 256);

    float* out = (float*)d_out;

    const int NBB = 512;                                  // bucket blocks
    const int WTB = (256 * 128 + 128 * 128 + 255) / 256;  // 192 weight blocks
    const int GB = (N + 127) / 128;                       // 782 gemm blocks

    // K0: weight cvt + zero bcnt
    cvt_zero_k<<<WTB + 1, 256, 0, stream>>>(W1, W2, Wt1, Wt2, bcnt, WTB);
    // K1: bucket-binning || gemm1 (unscaled) in one kernel
    fused1_k<<<NBB + GB, 256, 0, stream>>>(src, dst, bcnt, tmp, E, N, NBB, x, Wt1, hb, N);
    // K2: per-bucket scan (inline 196-prefix) + dinv + rowptr + einfo scatter
    scatter2_k<<<NBKT, 1024, 0, stream>>>(tmp, bcnt, dinv, rowptr, einfo, N, NBKT);
    // K3: agg1 applies dinv[s] per source row (fma)
    agg_k<true, true><<<(N + 3) / 4, 256, 0, stream>>>(hb, rowptr, einfo, dinv, b1, a1b, N);
    // K4: layer-2 GEMM (dinv-scaled epilogue)
    gemm2_k<<<GB, 256, 0, stream>>>(a1b, Wt2, dinv, hb, N, DH);
    // K5: agg2 -> fp32 out
    agg_k<false, false><<<(N + 3) / 4, 256, 0, stream>>>(hb, rowptr, einfo, dinv, b2, out, N);
}